// Round 1
// baseline (375.658 us; speedup 1.0000x reference)
//
#include <hip/hip_runtime.h>
#include <hip/hip_bf16.h>
#include <math.h>

#define DEVINL __device__ __forceinline__

typedef __bf16 bf16x8 __attribute__((ext_vector_type(8)));
typedef short short8_t __attribute__((ext_vector_type(8)));
typedef float f32x4 __attribute__((ext_vector_type(4)));
typedef unsigned short u16;
typedef unsigned int u32;

#define B_ 16
#define L_ 2048
#define DIM_ 256
#define BL_ (B_*L_)

DEVINL u16 f2bf(float f){
  __hip_bfloat16 h = __float2bfloat16(f);
  return __builtin_bit_cast(u16, h);
}
DEVINL float bf2f(u16 u){
  __hip_bfloat16 h = __builtin_bit_cast(__hip_bfloat16, u);
  return __bfloat162float(h);
}
DEVINL float siluf(float x){ return x / (1.f + __expf(-x)); }
DEVINL f32x4 mfma16(bf16x8 a, bf16x8 b, f32x4 c){
  return __builtin_amdgcn_mfma_f32_16x16x32_bf16(a, b, c, 0, 0, 0);
}
DEVINL bf16x8 ld_bf8(const u16* p){
  return __builtin_bit_cast(bf16x8, *(const short8_t*)p);
}

// ---------------- P1: weight prep (transpose to [n][k] bf16) ----------------
__global__ __launch_bounds__(256) void prep_weights(
    const float* __restrict__ w_h, const float* __restrict__ w_qk,
    const float* __restrict__ w_o, const float* __restrict__ w_p,
    const float* __restrict__ b_h, const float* __restrict__ b_qk,
    u16* __restrict__ wT1, u16* __restrict__ woT,
    u16* __restrict__ wp_bf, float* __restrict__ bias384){
  int idx = blockIdx.x*256 + threadIdx.x;
  const int total = 384*256 + 256*128 + 512*256 + 384;
  for (; idx < total; idx += gridDim.x*256){
    int i = idx;
    if (i < 384*256){
      int n = i >> 8, k = i & 255;
      float v = (n < 256) ? w_h[k*256 + n] : w_qk[k*128 + (n-256)];
      wT1[i] = f2bf(v);
    } else if ((i -= 384*256) < 256*128){
      int n = i >> 7, k = i & 127;
      woT[i] = f2bf(w_o[k*256 + n]);
    } else if ((i -= 256*128) < 512*256){
      wp_bf[i] = f2bf(w_p[i]);
    } else {
      i -= 512*256;
      bias384[i] = (i < 256) ? b_h[i] : b_qk[i-256];
    }
  }
}

// ---------------- P2: rope tables ----------------
__global__ __launch_bounds__(256) void prep_rope(float* __restrict__ ctab, float* __restrict__ stab){
  int idx = blockIdx.x*256 + threadIdx.x; // 2048*64
  if (idx >= 2048*64) return;
  int l = idx >> 6, f = idx & 63;
  float inv = powf(10000.f, -(float)(2*f) * (1.f/128.f));
  float ang = (float)l * inv;
  ctab[idx] = cosf(ang);
  stab[idx] = sinf(ang);
}

// ---------------- K1: layernorm (b,c,l)->bf16 (b,l,c) ----------------
__global__ __launch_bounds__(256) void ln_kernel(const float* __restrict__ x,
    const float* __restrict__ ln_g, const float* __restrict__ ln_b,
    u16* __restrict__ normed){
  __shared__ float xs[256][65];
  __shared__ float redsum[4][64], redsq[4][64];
  __shared__ float mu_s[64], rs_s[64];
  int b = blockIdx.y, lt = blockIdx.x;
  int tid = threadIdx.x;
  int tx = tid & 63, ty = tid >> 6;
  size_t xbase = (size_t)b*DIM_*L_ + (size_t)lt*64;
  float s = 0.f, s2 = 0.f;
  for (int c = ty; c < 256; c += 4){
    float v = x[xbase + (size_t)c*L_ + tx];
    xs[c][tx] = v;
    s += v; s2 += v*v;
  }
  redsum[ty][tx] = s; redsq[ty][tx] = s2;
  __syncthreads();
  if (ty == 0){
    float ss = redsum[0][tx]+redsum[1][tx]+redsum[2][tx]+redsum[3][tx];
    float qq = redsq[0][tx]+redsq[1][tx]+redsq[2][tx]+redsq[3][tx];
    float mu = ss * (1.f/256.f);
    float var = qq * (1.f/256.f) - mu*mu;
    mu_s[tx] = mu;
    rs_s[tx] = rsqrtf(var + 1e-5f);
  }
  __syncthreads();
  for (int i = 0; i < 8; i++){
    int chunk = tid + 256*i;
    int l = chunk >> 5, c0 = (chunk & 31) * 8;
    float mu = mu_s[l], rs = rs_s[l];
    short8_t outv;
    #pragma unroll
    for (int j = 0; j < 8; j++){
      int c = c0 + j;
      float v = (xs[c][l] - mu) * rs * ln_g[c] + ln_b[c];
      outv[j] = (short)f2bf(v);
    }
    *(short8_t*)&normed[((size_t)(b*L_) + lt*64 + l)*256 + c0] = outv;
  }
}

// ---------------- K2: GEMM1 normed @ [w_h | w_qk] + bias -> hidz bf16 (b,l,384)
__global__ __launch_bounds__(256) void gemm_hid(const u16* __restrict__ normed,
    const u16* __restrict__ wT1, const float* __restrict__ bias384,
    u16* __restrict__ hidz){
  __shared__ u16 atile[64*256];
  int b = blockIdx.y, lt = blockIdx.x;
  int tid = threadIdx.x;
  for (int i = 0; i < 8; i++){
    int chunk = tid + 256*i;
    int row = chunk >> 5, kc = chunk & 31;
    int byte = (row*512 + kc*16) ^ ((row & 7) << 4);
    *(short8_t*)((char*)atile + byte) =
        *(const short8_t*)&normed[((size_t)(b*L_) + lt*64 + row)*256 + kc*8];
  }
  __syncthreads();
  int lane = tid & 63, wave = tid >> 6;
  int l15 = lane & 15, lg = lane >> 4;
  int n0 = wave * 96;
  f32x4 zero = {0.f,0.f,0.f,0.f};
  f32x4 acc[4][6];
  for (int m=0;m<4;m++) for (int n=0;n<6;n++) acc[m][n]=zero;
  for (int ks = 0; ks < 8; ks++){
    bf16x8 a[4];
    #pragma unroll
    for (int m = 0; m < 4; m++){
      int row = m*16 + l15;
      int byte = (row*512 + ks*64 + lg*16) ^ ((row & 7) << 4);
      a[m] = __builtin_bit_cast(bf16x8, *(const short8_t*)((char*)atile + byte));
    }
    #pragma unroll
    for (int n = 0; n < 6; n++){
      int col = n0 + n*16 + l15;
      bf16x8 bfrag = ld_bf8(&wT1[col*256 + ks*32 + lg*8]);
      #pragma unroll
      for (int m = 0; m < 4; m++)
        acc[m][n] = mfma16(a[m], bfrag, acc[m][n]);
    }
  }
  for (int n = 0; n < 6; n++){
    int col = n0 + n*16 + l15;
    float bias = bias384[col];
    for (int m = 0; m < 4; m++)
      #pragma unroll
      for (int r = 0; r < 4; r++){
        size_t row = (size_t)(b*L_) + lt*64 + m*16 + lg*4 + r;
        hidz[row*384 + col] = f2bf(acc[m][n][r] + bias);
      }
  }
}

// ---------------- K3: pointwise silu / rope -> u, vT, q, k ----------------
__global__ __launch_bounds__(256) void pointwise_kernel(const u16* __restrict__ hidz,
    const float* __restrict__ ctab, const float* __restrict__ stab,
    const float* __restrict__ gamma, const float* __restrict__ beta,
    float* __restrict__ u, u16* __restrict__ vT,
    u16* __restrict__ qm, u16* __restrict__ km){
  __shared__ u16 vs[64][130];
  int b = blockIdx.y, lt = blockIdx.x;
  int tid = threadIdx.x;
  size_t rowbase = (size_t)(b*L_) + lt*64;
  for (int i = 0; i < 32; i++){
    int idx = tid + 256*i;
    int l = idx >> 7, d = idx & 127;
    size_t row = rowbase + l;
    u[row*128 + d] = siluf(bf2f(hidz[row*384 + 128 + d]));
    vs[l][d] = hidz[row*384 + d];
  }
  __syncthreads();
  for (int i = 0; i < 4; i++){
    int chunk = tid + 256*i;
    int d = chunk >> 3, lc = (chunk & 7)*8;
    short8_t vv;
    #pragma unroll
    for (int j = 0; j < 8; j++)
      vv[j] = (short)f2bf(siluf(bf2f(vs[lc + j][d])));
    *(short8_t*)&vT[((size_t)b*128 + d)*2048 + lt*64 + lc] = vv;
  }
  for (int i = 0; i < 16; i++){
    int idx = tid + 256*i;
    int l = idx >> 6, f = idx & 63;
    size_t row = rowbase + l;
    u32 zz = *(const u32*)&hidz[row*384 + 256 + 2*f];
    float z1 = siluf(bf2f((u16)(zz & 0xffffu)));
    float z2 = siluf(bf2f((u16)(zz >> 16)));
    int gl = lt*64 + l;
    float c = ctab[gl*64 + f], s = stab[gl*64 + f];
    float q1 = z1*gamma[2*f]   + beta[2*f];
    float q2 = z2*gamma[2*f+1] + beta[2*f+1];
    u32 qp = (u32)f2bf(q1*c - q2*s) | ((u32)f2bf(q1*s + q2*c) << 16);
    *(u32*)&qm[row*128 + 2*f] = qp;
    float k1 = z1*gamma[128 + 2*f]   + beta[128 + 2*f];
    float k2 = z2*gamma[128 + 2*f+1] + beta[128 + 2*f+1];
    u32 kp = (u32)f2bf(k1*c - k2*s) | ((u32)f2bf(k1*s + k2*c) << 16);
    *(u32*)&km[row*128 + 2*f] = kp;
  }
}

// ---------------- K4: flash attention ----------------
__global__ __launch_bounds__(256) void attn_kernel(const u16* __restrict__ qm,
    const u16* __restrict__ km, const u16* __restrict__ vT,
    float* __restrict__ attnO){
  __shared__ u16 pbuf[4][16][32];
  int b = blockIdx.y, qt = blockIdx.x;
  int tid = threadIdx.x;
  int lane = tid & 63, wave = tid >> 6;
  int l15 = lane & 15, lg = lane >> 4;
  int qrow0 = qt*64 + wave*16;
  size_t qbase = ((size_t)(b*L_) + qrow0 + l15) * 128;
  bf16x8 qf[4];
  #pragma unroll
  for (int ks = 0; ks < 4; ks++)
    qf[ks] = ld_bf8(&qm[qbase + ks*32 + lg*8]);
  f32x4 zero = {0.f,0.f,0.f,0.f};
  f32x4 o[8];
  #pragma unroll
  for (int n = 0; n < 8; n++) o[n] = zero;
  float m[4], lsum[4];
  #pragma unroll
  for (int r = 0; r < 4; r++){ m[r] = -1e30f; lsum[r] = 0.f; }
  const float inv_L = 1.f/2048.f;
  const u16* kb = km + (size_t)(b*L_)*128;
  const u16* vb = vT + (size_t)b*128*2048;
  for (int j0 = 0; j0 < 2048; j0 += 32){
    f32x4 s0 = zero, s1 = zero;
    #pragma unroll
    for (int ks = 0; ks < 4; ks++){
      bf16x8 k0 = ld_bf8(&kb[(size_t)(j0 + l15)*128 + ks*32 + lg*8]);
      bf16x8 k1 = ld_bf8(&kb[(size_t)(j0 + 16 + l15)*128 + ks*32 + lg*8]);
      s0 = mfma16(qf[ks], k0, s0);
      s1 = mfma16(qf[ks], k1, s1);
    }
    float corr[4];
    #pragma unroll
    for (int r = 0; r < 4; r++){
      float a0 = s0[r] * inv_L, a1 = s1[r] * inv_L;
      float t = fmaxf(a0, a1);
      t = fmaxf(t, __shfl_xor(t, 1));
      t = fmaxf(t, __shfl_xor(t, 2));
      t = fmaxf(t, __shfl_xor(t, 4));
      t = fmaxf(t, __shfl_xor(t, 8));
      float mn = fmaxf(m[r], t);
      float cr = __expf(m[r] - mn);
      corr[r] = cr;
      m[r] = mn;
      float p0 = __expf(a0 - mn), p1 = __expf(a1 - mn);
      float ps = p0 + p1;
      ps += __shfl_xor(ps, 1);
      ps += __shfl_xor(ps, 2);
      ps += __shfl_xor(ps, 4);
      ps += __shfl_xor(ps, 8);
      lsum[r] = lsum[r]*cr + ps;
      s0[r] = p0; s1[r] = p1;
    }
    #pragma unroll
    for (int n = 0; n < 8; n++)
      #pragma unroll
      for (int r = 0; r < 4; r++)
        o[n][r] *= corr[r];
    #pragma unroll
    for (int r = 0; r < 4; r++){
      int rw = lg*4 + r;
      pbuf[wave][rw][l15]      = f2bf(s0[r]);
      pbuf[wave][rw][l15 + 16] = f2bf(s1[r]);
    }
    bf16x8 pa = __builtin_bit_cast(bf16x8, *(const short8_t*)&pbuf[wave][l15][lg*8]);
    #pragma unroll
    for (int n = 0; n < 8; n++){
      bf16x8 vf = ld_bf8(&vb[(size_t)(n*16 + l15)*2048 + j0 + lg*8]);
      o[n] = mfma16(pa, vf, o[n]);
    }
  }
  #pragma unroll
  for (int r = 0; r < 4; r++){
    float inv = 1.f / lsum[r];
    size_t row = (size_t)(b*L_) + qrow0 + lg*4 + r;
    #pragma unroll
    for (int n = 0; n < 8; n++)
      attnO[row*128 + n*16 + l15] = o[n][r] * inv;
  }
}

// ---------------- K5: (u*V) @ w_o + b_o -> outbl bf16 (b,l,256) ----------------
__global__ __launch_bounds__(256) void gemm_out(const float* __restrict__ attnO,
    const float* __restrict__ u, const u16* __restrict__ woT,
    const float* __restrict__ b_o, u16* __restrict__ outbl){
  __shared__ u16 atile[64*128];
  int b = blockIdx.y, lt = blockIdx.x;
  int tid = threadIdx.x;
  size_t rowbase = (size_t)(b*L_) + lt*64;
  for (int i = 0; i < 8; i++){
    int idx = tid + 256*i;
    int row = idx >> 5, d0 = (idx & 31)*4;
    size_t gofs = (rowbase + row)*128 + d0;
    float4 av = *(const float4*)&attnO[gofs];
    float4 uv = *(const float4*)&u[gofs];
    uint2 pk;
    pk.x = (u32)f2bf(av.x*uv.x) | ((u32)f2bf(av.y*uv.y) << 16);
    pk.y = (u32)f2bf(av.z*uv.z) | ((u32)f2bf(av.w*uv.w) << 16);
    int byte = (row*256 + d0*2) ^ ((row & 7) << 4);
    *(uint2*)((char*)atile + byte) = pk;
  }
  __syncthreads();
  int lane = tid & 63, wave = tid >> 6;
  int l15 = lane & 15, lg = lane >> 4;
  int n0 = wave*64;
  f32x4 zero = {0.f,0.f,0.f,0.f};
  f32x4 acc[4][4];
  for (int m=0;m<4;m++) for(int n=0;n<4;n++) acc[m][n]=zero;
  for (int ks = 0; ks < 4; ks++){
    bf16x8 a[4];
    #pragma unroll
    for (int m = 0; m < 4; m++){
      int row = m*16 + l15;
      int byte = (row*256 + ks*64 + lg*16) ^ ((row&7)<<4);
      a[m] = __builtin_bit_cast(bf16x8, *(const short8_t*)((char*)atile + byte));
    }
    #pragma unroll
    for (int n = 0; n < 4; n++){
      int col = n0 + n*16 + l15;
      bf16x8 bf = ld_bf8(&woT[col*128 + ks*32 + lg*8]);
      #pragma unroll
      for (int m = 0; m < 4; m++) acc[m][n] = mfma16(a[m], bf, acc[m][n]);
    }
  }
  for (int n = 0; n < 4; n++){
    int col = n0 + n*16 + l15;
    float bias = b_o[col];
    for (int m = 0; m < 4; m++)
      #pragma unroll
      for (int r = 0; r < 4; r++){
        size_t row = rowbase + m*16 + lg*4 + r;
        outbl[row*256 + col] = f2bf(acc[m][n][r] + bias);
      }
  }
}

// ---------------- K6: proj GEMM + residual/skip epilogue ----------------
__global__ __launch_bounds__(256) void gemm_proj(const u16* __restrict__ outbl,
    const u16* __restrict__ wp_bf, const float* __restrict__ b_p,
    const float* __restrict__ x, float* __restrict__ outp){
  __shared__ u16 atile[32*256];
  int b = blockIdx.y, lt = blockIdx.x; // 64 tiles of 32 rows
  int tid = threadIdx.x;
  size_t rowbase = (size_t)(b*L_) + lt*32;
  for (int i = 0; i < 4; i++){
    int chunk = tid + 256*i;
    int row = chunk >> 5, kc = chunk & 31;
    int byte = (row*512 + kc*16) ^ ((row & 7) << 4);
    *(short8_t*)((char*)atile + byte) = *(const short8_t*)&outbl[(rowbase + row)*256 + kc*8];
  }
  __syncthreads();
  int lane = tid & 63, wave = tid >> 6;
  int l15 = lane & 15, lg = lane >> 4;
  int n0 = wave*128;
  f32x4 zero = {0.f,0.f,0.f,0.f};
  f32x4 acc[2][8];
  for (int m=0;m<2;m++) for(int n=0;n<8;n++) acc[m][n]=zero;
  for (int ks = 0; ks < 8; ks++){
    bf16x8 a[2];
    #pragma unroll
    for (int m = 0; m < 2; m++){
      int row = m*16 + l15;
      int byte = (row*512 + ks*64 + lg*16) ^ ((row&7)<<4);
      a[m] = __builtin_bit_cast(bf16x8, *(const short8_t*)((char*)atile + byte));
    }
    #pragma unroll
    for (int n = 0; n < 8; n++){
      int col = n0 + n*16 + l15;
      bf16x8 bf = ld_bf8(&wp_bf[col*256 + ks*32 + lg*8]);
      #pragma unroll
      for (int m = 0; m < 2; m++) acc[m][n] = mfma16(a[m], bf, acc[m][n]);
    }
  }
  const float inv_s2 = 0.70710678118654752f;
  for (int n = 0; n < 8; n++){
    int o = n0 + n*16 + l15;
    float bias = b_p[o];
    for (int m = 0; m < 2; m++){
      int lofs = lt*32 + m*16 + lg*4;
      float4 v;
      v.x = acc[m][n][0] + bias; v.y = acc[m][n][1] + bias;
      v.z = acc[m][n][2] + bias; v.w = acc[m][n][3] + bias;
      if (o < 256){
        size_t xofs = ((size_t)b*256 + o)*L_ + lofs;
        float4 xv = *(const float4*)&x[xofs];
        v.x = (xv.x + v.x)*inv_s2; v.y = (xv.y + v.y)*inv_s2;
        v.z = (xv.z + v.z)*inv_s2; v.w = (xv.w + v.w)*inv_s2;
        *(float4*)&outp[xofs] = v;
      } else {
        size_t oofs = (size_t)B_*256*L_ + ((size_t)b*256 + (o-256))*L_ + lofs;
        *(float4*)&outp[oofs] = v;
      }
    }
  }
}

extern "C" void kernel_launch(void* const* d_in, const int* in_sizes, int n_in,
                              void* d_out, int out_size, void* d_ws, size_t ws_size,
                              hipStream_t stream){
  const float* x    = (const float*)d_in[0];
  const float* ln_g = (const float*)d_in[1];
  const float* ln_b = (const float*)d_in[2];
  const float* w_h  = (const float*)d_in[3];
  const float* b_h  = (const float*)d_in[4];
  const float* w_qk = (const float*)d_in[5];
  const float* b_qk = (const float*)d_in[6];
  const float* gamma= (const float*)d_in[7];
  const float* beta = (const float*)d_in[8];
  const float* w_o  = (const float*)d_in[9];
  const float* b_o  = (const float*)d_in[10];
  const float* w_p  = (const float*)d_in[11];
  const float* b_p  = (const float*)d_in[12];
  char* ws = (char*)d_ws;
  // layout (bytes); hidz dead after K3 -> outbl reuses offset 0
  u16*  hidz   = (u16*)(ws + 0);                 // 25,165,824
  u16*  outbl  = (u16*)(ws + 0);                 // 16,777,216 (reuse)
  u16*  normed = (u16*)(ws + 25165824);          // 16,777,216
  u16*  qm     = (u16*)(ws + 41943040);          //  8,388,608
  u16*  km     = (u16*)(ws + 50331648);          //  8,388,608
  u16*  vT     = (u16*)(ws + 58720256);          //  8,388,608
  float* u     = (float*)(ws + 67108864);        // 16,777,216
  float* attnO = (float*)(ws + 83886080);        // 16,777,216
  u16*  wT1    = (u16*)(ws + 100663296);         //    196,608
  u16*  woT    = (u16*)(ws + 100663296 + 196608);//     65,536
  u16*  wp_bf  = (u16*)(ws + 100663296 + 262144);//    262,144
  float* bias384=(float*)(ws + 100663296 + 524288); //   2,048
  float* ctab  = (float*)(ws + 100663296 + 526336); // 524,288
  float* stab  = ctab + 2048*64;                    // 524,288
  float* outp  = (float*)d_out;

  prep_weights<<<dim3(512),dim3(256),0,stream>>>(w_h,w_qk,w_o,w_p,b_h,b_qk,wT1,woT,wp_bf,bias384);
  prep_rope<<<dim3(512),dim3(256),0,stream>>>(ctab,stab);
  ln_kernel<<<dim3(32,16),dim3(256),0,stream>>>(x,ln_g,ln_b,normed);
  gemm_hid<<<dim3(32,16),dim3(256),0,stream>>>(normed,wT1,bias384,hidz);
  pointwise_kernel<<<dim3(32,16),dim3(256),0,stream>>>(hidz,ctab,stab,gamma,beta,u,vT,qm,km);
  attn_kernel<<<dim3(32,16),dim3(256),0,stream>>>(qm,km,vT,attnO);
  gemm_out<<<dim3(32,16),dim3(256),0,stream>>>(attnO,u,woT,b_o,outbl);
  gemm_proj<<<dim3(64,16),dim3(256),0,stream>>>(outbl,wp_bf,b_p,x,outp);
}